// Round 1
// baseline (8174.340 us; speedup 1.0000x reference)
//
#include <hip/hip_runtime.h>

// RNN: h_t = tanh(W_hh h_{t-1} + b_hh + W_xh emb[X_t] + b_xh)
// N=64, L=2048, V=32000, H=512.  Output (N,L,H) fp32 = 256 MB.
//
// K1: Xh' = emb[X] @ W_xh^T + b_xh + b_hh  (fp16 MFMA, fp32 accum) -> written INTO d_out.
// K2: 32 pairs of WGs (64 blocks x 512 thr). Each WG: batch rows {2p,2p+1}, cols half
//     [256*side, 256*side+256). W_hh half resident in VGPRs as fp16 MFMA A-fragments
//     (128 VGPR/lane). Own-K from LDS, partner-K via global mailbox + step-counter flag
//     (relaxed agent-scope atomics = coherent on any XCD placement; spin capped -> no hang).

typedef _Float16 half8 __attribute__((ext_vector_type(8)));
typedef float    f32x4 __attribute__((ext_vector_type(4)));

#define MFMA_F16(A,B,C) __builtin_amdgcn_mfma_f32_16x16x32_f16(A,B,C,0,0,0)

static __device__ __forceinline__ half8 cvt8(const float* p){
  const f32x4* q = (const f32x4*)p;
  f32x4 a = q[0], b = q[1];
  half8 r;
  r[0]=(_Float16)a[0]; r[1]=(_Float16)a[1]; r[2]=(_Float16)a[2]; r[3]=(_Float16)a[3];
  r[4]=(_Float16)b[0]; r[5]=(_Float16)b[1]; r[6]=(_Float16)b[2]; r[7]=(_Float16)b[3];
  return r;
}

static __device__ __forceinline__ float tanh_fast(float z){
  // tanh(z) = 1 - 2/(exp(2z)+1); saturates correctly at +/-inf of exp
  float e = __expf(2.0f*z);
  return 1.0f - 2.0f/(e + 1.0f);
}

// ---------------- Kernel 1: Xh' = E @ Wxh^T + (bxh + bhh) -> d_out ----------------
// 64x64 tile per 256-thread block, 4 waves, wave = 2x2 of 16x16 tiles. No LDS:
// A-frags gathered straight from emb rows (L3), B-frags from W_xh rows (L2).
__global__ __launch_bounds__(256) void k_xh(
    const int* __restrict__ X, const float* __restrict__ emb,
    const float* __restrict__ Wxh, const float* __restrict__ bxh,
    const float* __restrict__ bhh, float* __restrict__ out)
{
  const int bid = blockIdx.x;
  const int bm = bid >> 3;        // 2048 M-blocks of 64 rows (m = n*2048 + t)
  const int bn = bid & 7;         // 8 N-blocks of 64 cols
  const int tid = threadIdx.x;
  const int w  = tid >> 6;
  const int l  = tid & 63;
  const int lr = l & 15, lq = l >> 4;

  const int mbase = bm*64 + (w>>1)*32;
  const int nbase = bn*64 + (w&1)*32;

  const int tok0 = X[mbase + lr];
  const int tok1 = X[mbase + 16 + lr];
  const int c0 = nbase + lr;
  const int c1 = nbase + 16 + lr;
  const float bs0 = bxh[c0] + bhh[c0];
  const float bs1 = bxh[c1] + bhh[c1];

  const float* a0 = emb + (long long)tok0*512 + lq*8;
  const float* a1 = emb + (long long)tok1*512 + lq*8;
  const float* b0 = Wxh + (long long)c0*512 + lq*8;
  const float* b1 = Wxh + (long long)c1*512 + lq*8;

  f32x4 acc00 = {0,0,0,0}, acc01 = {0,0,0,0}, acc10 = {0,0,0,0}, acc11 = {0,0,0,0};

  #pragma unroll
  for (int ks=0; ks<16; ++ks){
    half8 A0 = cvt8(a0 + ks*32);
    half8 A1 = cvt8(a1 + ks*32);
    half8 B0 = cvt8(b0 + ks*32);
    half8 B1 = cvt8(b1 + ks*32);
    acc00 = MFMA_F16(A0, B0, acc00);
    acc01 = MFMA_F16(A0, B1, acc01);
    acc10 = MFMA_F16(A1, B0, acc10);
    acc11 = MFMA_F16(A1, B1, acc11);
  }
  // D layout: col = lane&15 (N), row = 4*(lane>>4)+r (M)
  #pragma unroll
  for (int r=0; r<4; ++r){
    const long long m0 = mbase + 4*lq + r;
    const long long m1 = m0 + 16;
    out[m0*512 + c0] = acc00[r] + bs0;
    out[m0*512 + c1] = acc01[r] + bs1;
    out[m1*512 + c0] = acc10[r] + bs0;
    out[m1*512 + c1] = acc11[r] + bs1;
  }
}

// ---------------- Kernel 2: the recurrence ----------------
// 64 blocks x 512 thr. pair = (b&7)*4 + (b>>4), side = (b>>3)&1, partner = b^8
// (partner shares blockIdx%8 -> same XCD under round-robin; atomics keep it correct anyway).
__global__ __launch_bounds__(512, 2) void k_rnn(
    const float* __restrict__ Whh,
    float* out,
    unsigned long long* mb,      // mailbox: 64 WGs * 256 ull ([buf2][n2][256 f16])
    unsigned int* flags)         // 64 step counters
{
  const int b = blockIdx.x;
  const int side    = (b>>3)&1;
  const int pair    = (b&7)*4 + (b>>4);
  const int partner = b ^ 8;
  const int tid = threadIdx.x;
  const int w = tid >> 6;          // 8 waves; wave owns cols [256*side+32w, +32)
  const int l = tid & 63;
  const int lr = l & 15, lq = l >> 4;
  const int ln = l & 1;            // batch-row index used for h B-frags (dup for lr>=2)

  __shared__ _Float16 hl[2][2][264];   // [buf][n][own k-local], stride-padded (528 B)

  for (int i = tid; i < 2*2*264; i += 512) (&hl[0][0][0])[i] = (_Float16)0.0f;

  // W_hh fragments (A-operand: row i = output col c = lane&15 within 16-tile,
  // k = 8*(lane>>4)+{0..7} per 32-K step). Slots [0,8) = own-half K, [8,16) = partner-half.
  const int cA = side*256 + w*32 + lr;
  const int cB = cA + 16;
  half8 WfA[16], WfB[16];
  #pragma unroll
  for (int ks=0; ks<8; ++ks){
    const int kown = (side*8 + ks)*32 + lq*8;
    const int kpar = ((side^1)*8 + ks)*32 + lq*8;
    WfA[ks]   = cvt8(Whh + (long long)cA*512 + kown);
    WfB[ks]   = cvt8(Whh + (long long)cB*512 + kown);
    WfA[8+ks] = cvt8(Whh + (long long)cA*512 + kpar);
    WfB[8+ks] = cvt8(Whh + (long long)cB*512 + kpar);
  }
  __syncthreads();

  const int n_row = pair*2 + ln;
  const long long row_base = (long long)n_row * 2048 * 512;
  const int ccol = side*256 + w*32 + lq*4;
  unsigned long long* mb_me = mb + (long long)b*256;
  unsigned long long* mb_pt = mb + (long long)partner*256;

  for (int t=0; t<2048; ++t){
    const int bufc = t & 1, bufp = bufc ^ 1;

    // prefetch xh' (K1 output lives in d_out at the slot we'll overwrite with h_t)
    f32x4 xh0 = {0,0,0,0}, xh1 = {0,0,0,0};
    long long obase = 0;
    if (lr < 2){
      obase = row_base + (long long)t*512 + ccol;
      xh0 = *(const f32x4*)(out + obase);
      xh1 = *(const f32x4*)(out + obase + 16);
    }

    f32x4 acc0 = {0,0,0,0}, acc1 = {0,0,0,0};

    // phase 1: own-half K from LDS (h B-frag: col j = n (dup l&1), k = 8*(l>>4)+{0..7})
    #pragma unroll
    for (int ks=0; ks<8; ++ks){
      half8 hf = *(const half8*)(&hl[bufp][ln][ks*32 + lq*8]);
      acc0 = MFMA_F16(WfA[ks], hf, acc0);
      acc1 = MFMA_F16(WfB[ks], hf, acc1);
    }

    // phase 2: partner-half K from mailbox (slot bufp holds partner h_{t-1})
    if (t > 0){
      {
        int spin = 0;
        while (__hip_atomic_load(&flags[partner], __ATOMIC_RELAXED, __HIP_MEMORY_SCOPE_AGENT)
                 < (unsigned)t && ++spin < (1<<20)) {}
      }
      unsigned long long* mp = mb_pt + (long long)bufp*128 + ln*64;
      #pragma unroll
      for (int ks=0; ks<8; ++ks){
        const int ui = ks*8 + lq*2;
        unsigned long long u0 = __hip_atomic_load(&mp[ui],   __ATOMIC_RELAXED, __HIP_MEMORY_SCOPE_AGENT);
        unsigned long long u1 = __hip_atomic_load(&mp[ui+1], __ATOMIC_RELAXED, __HIP_MEMORY_SCOPE_AGENT);
        union { unsigned long long u[2]; half8 v; } cv;
        cv.u[0] = u0; cv.u[1] = u1;
        acc0 = MFMA_F16(WfA[8+ks], cv.v, acc0);
        acc1 = MFMA_F16(WfB[8+ks], cv.v, acc1);
      }
    }

    // epilogue: z = acc + xh'; h = tanh(z); write fp32 out, fp16 to LDS + mailbox
    if (lr < 2){
      f32x4 h0, h1;
      #pragma unroll
      for (int r=0; r<4; ++r){
        h0[r] = tanh_fast(acc0[r] + xh0[r]);
        h1[r] = tanh_fast(acc1[r] + xh1[r]);
      }
      *(f32x4*)(out + obase)      = h0;
      *(f32x4*)(out + obase + 16) = h1;
      union { _Float16 h[4]; unsigned long long u; } p0, p1;
      #pragma unroll
      for (int r=0; r<4; ++r){ p0.h[r] = (_Float16)h0[r]; p1.h[r] = (_Float16)h1[r]; }
      const int cl = w*32 + lq*4;
      *(unsigned long long*)(&hl[bufc][ln][cl])      = p0.u;
      *(unsigned long long*)(&hl[bufc][ln][cl + 16]) = p1.u;
      unsigned long long* mm = mb_me + (long long)bufc*128 + ln*64;
      __hip_atomic_store(&mm[cl>>2],       p0.u, __ATOMIC_RELAXED, __HIP_MEMORY_SCOPE_AGENT);
      __hip_atomic_store(&mm[(cl>>2) + 4], p1.u, __ATOMIC_RELAXED, __HIP_MEMORY_SCOPE_AGENT);
    }

    __syncthreads();   // drains vmcnt for all waves -> mailbox data globally visible
    if (tid == 0)
      __hip_atomic_store(&flags[b], (unsigned)(t+1), __ATOMIC_RELAXED, __HIP_MEMORY_SCOPE_AGENT);
  }
}

extern "C" void kernel_launch(void* const* d_in, const int* in_sizes, int n_in,
                              void* d_out, int out_size, void* d_ws, size_t ws_size,
                              hipStream_t stream)
{
  const int*   X    = (const int*)  d_in[0];
  const float* emb  = (const float*)d_in[1];
  const float* Whh  = (const float*)d_in[2];
  const float* bhh  = (const float*)d_in[3];
  const float* Wxh  = (const float*)d_in[4];
  const float* bxh  = (const float*)d_in[5];
  float* out = (float*)d_out;

  unsigned long long* mb   = (unsigned long long*)d_ws;              // 64*2048 B
  unsigned int*       flags = (unsigned int*)((char*)d_ws + 64*2048); // 256 B

  hipMemsetAsync(flags, 0, 64*sizeof(unsigned int), stream);
  hipLaunchKernelGGL(k_xh,  dim3(16384), dim3(256), 0, stream, X, emb, Wxh, bxh, bhh, out);
  hipLaunchKernelGGL(k_rnn, dim3(64),    dim3(512), 0, stream, Whh, out, mb, flags);
}